// Round 11
// baseline (3015.100 us; speedup 1.0000x reference)
//
#include <hip/hip_runtime.h>
#include <cstdint>
#include <cstddef>
#include <cmath>

// ---------------------------------------------------------------------------
// Pipeline:
//   A0 k_warm   : pull x into L2/L3 (full-GPU streaming read, ~13us)
//   A1 k_carry  : exact sequential fl cumsum chains (8 blocks producer-
//                 consumer LDS double-buffer), 256-row checkpoints only
//   A2 k_spread : 512 blocks replay each 256-row chunk from its exact carry
//   B  k_diffs  : exact numpy-pairwise variance->diffs (float4 loads)
//   C  k_hist1/k_sel_hi/k_hist2/k_sel_lo : exact top-32768 radix select
//   D  k_keep   : keep flags, stable tie ranks
//   E  k_segment: per-batch boundary lists + frame->segment map
//   F  k_prefix : ragged row offsets
//   G  k_pool   : segment means (comp)
//   H  k_gi     : gi = comp @ W_ih^T + biases  [fp32 GEMM]
//   I  k_gru    : sequential GRU, 512 thr. Allocator law (5 data points):
//                 per-wave budget = 512/(waves per SIMD); hipcc never
//                 voluntarily uses the AGPR half -> it memory-spilled every
//                 >cap design (WRITE_SIZE +17-24MB each time). Fix: wr[64]
//                 in VGPRs, wz/wn[128] in AGPRs via explicit
//                 v_accvgpr_write/read inline asm (1-cyc VALU moves).
//   J  k_scatter: out[b,t,:] = gru_out[b, seg(t), :]
// ---------------------------------------------------------------------------

#define NPOS 65537
#define KSEL 32768u

typedef _Float16 f16x2 __attribute__((ext_vector_type(2)));
typedef _Float16 f16x8 __attribute__((ext_vector_type(8)));

#if defined(__has_builtin)
#if __has_builtin(__builtin_amdgcn_fdot2)
#define HAVE_FDOT2 1
#endif
#endif

__device__ __forceinline__ float fdot2f(f16x2 a, f16x2 b, float c) {
#ifdef HAVE_FDOT2
  return __builtin_amdgcn_fdot2(a, b, c, false);
#else
  c += (float)a.x * (float)b.x;
  c += (float)a.y * (float)b.y;
  return c;
#endif
}

__device__ __forceinline__ unsigned pack_f16x2(float lo, float hi) {
  f16x2 p; p.x = (_Float16)lo; p.y = (_Float16)hi;
  union { f16x2 h; unsigned u; } cv; cv.h = p;
  return cv.u;
}

__device__ __forceinline__ f16x2 as_f16x2(unsigned u) {
  union { unsigned u; f16x2 h; } cv; cv.u = u;
  return cv.h;
}

// --------------------------- A0: warm x into cache -------------------------
__global__ __launch_bounds__(256) void k_warm(const float4* __restrict__ x4,
                                              float* __restrict__ sink) {
  size_t i = (size_t)blockIdx.x * 256 + threadIdx.x;
  float4 v = x4[i];
  float s = (v.x + v.y) + (v.z + v.w);
  if (s == 1.23456789e-33f) sink[0] = s;  // deterministically false; keeps loads
}

// --------------------------- A1: carry chains ------------------------------
__global__ __launch_bounds__(256) void k_carry(const float* __restrict__ x,
                                               float* __restrict__ carr) {
  __shared__ __align__(16) float lds[2 * 256 * 64];   // 128 KiB
  const int b = blockIdx.x;
  const int sq = b >> 2;
  const int j0 = (b & 3) * 64;
  const int wid = threadIdx.x >> 6;
  const int l = threadIdx.x & 63;

  if (wid != 0) {
    // ----- stagers -----
    const int wsel = wid - 1;   // 0..2; handles 4-row groups g with g%3==wsel
    const size_t lane_off = (size_t)(l >> 4) * 256 + (size_t)(l & 15) * 4;
    for (int c = 0; c <= 256; ++c) {
      if (c < 256) {
        const float* src = x + (size_t)c * 256 * 256 + j0 + lane_off;
        float* dbase = lds + (c & 1) * 16384;
        for (int g = wsel; g < 64; g += 3) {
          __builtin_amdgcn_global_load_lds(
              (const __attribute__((address_space(1))) void*)(src + (size_t)g * 1024),
              (__attribute__((address_space(3))) void*)(dbase + g * 256),
              16, 0, 0);
        }
      }
      asm volatile("s_waitcnt vmcnt(0)" ::: "memory");
      __builtin_amdgcn_sched_barrier(0);
      __builtin_amdgcn_s_barrier();
      __builtin_amdgcn_sched_barrier(0);
    }
  } else {
    // ----- chain wave -----
#pragma clang fp contract(off)
    __builtin_amdgcn_s_barrier();        // chunk 0 staged
    __builtin_amdgcn_sched_barrier(0);
    float acc = 0.f;
    float* cw = carr + ((size_t)sq * 256) * 256 + j0 + l;
    if (sq) {
      for (int c = 0; c < 256; ++c) {
        cw[(size_t)c * 256] = acc;       // carry BEFORE chunk c's rows
        const float* lp = lds + (c & 1) * 16384 + l;
#pragma unroll 16
        for (int r = 0; r < 256; ++r) {
          float v = lp[r * 64];
          v = v * v;                     // rounded square, then add (no FMA)
          acc = acc + v;
        }
        asm volatile("s_waitcnt lgkmcnt(0)" ::: "memory");
        __builtin_amdgcn_sched_barrier(0);
        __builtin_amdgcn_s_barrier();
        __builtin_amdgcn_sched_barrier(0);
      }
    } else {
      for (int c = 0; c < 256; ++c) {
        cw[(size_t)c * 256] = acc;
        const float* lp = lds + (c & 1) * 16384 + l;
#pragma unroll 16
        for (int r = 0; r < 256; ++r) {
          float v = lp[r * 64];
          acc = acc + v;
        }
        asm volatile("s_waitcnt lgkmcnt(0)" ::: "memory");
        __builtin_amdgcn_sched_barrier(0);
        __builtin_amdgcn_s_barrier();
        __builtin_amdgcn_sched_barrier(0);
      }
    }
  }
}

// --------------------------- A2: spread chunks -----------------------------
__global__ __launch_bounds__(256) void k_spread(const float* __restrict__ x,
                                                const float* __restrict__ carr,
                                                float* __restrict__ cs1,
                                                float* __restrict__ cs2) {
#pragma clang fp contract(off)
  const int blk = blockIdx.x;
  const int sq = blk >> 8;
  const int ch = blk & 255;
  const int col = threadIdx.x;
  float* dst = sq ? cs2 : cs1;
  float c = carr[((size_t)sq * 256 + ch) * 256 + col];
  const float* gp = x + (size_t)ch * 256 * 256 + col;
  float* sp = dst + ((size_t)ch * 256 + 1) * 256 + col;
  if (ch == 0) dst[col] = 0.f;        // p=0 row (enc zero prepend)
  float buf[4][8];
#pragma unroll
  for (int d = 0; d < 3; ++d)
#pragma unroll
    for (int u = 0; u < 8; ++u)
      buf[d][u] = gp[(size_t)(d * 8 + u) * 256];
  for (int g = 0; g < 8; ++g) {
#pragma unroll
    for (int d = 0; d < 4; ++d) {
      const int s = g * 4 + d;        // 8-row group (0..31)
      if (s + 3 < 32) {
        const float* ld = gp + (size_t)(s + 3) * 8 * 256;
#pragma unroll
        for (int u = 0; u < 8; ++u)
          buf[(d + 3) & 3][u] = ld[(size_t)u * 256];
      }
#pragma unroll
      for (int u = 0; u < 8; ++u) {
        float v = buf[d][u];
        if (sq) v = v * v;
        c = c + v;
        sp[(size_t)(s * 8 + u) * 256] = c;
      }
    }
  }
}

// --------------------------- B: exact diffs --------------------------------
__device__ __forceinline__ float dterm(float ap, float am, float bp, float bm) {
#pragma clang fp contract(off)
  float s1 = ap - am;
  float s2 = bp - bm;
  float t1 = s1 * 0.5f;
  float u = s2 * 0.5f;
  return u - t1 * t1;
}

__global__ __launch_bounds__(64) void k_diffs(const float* __restrict__ cs1,
                                              const float* __restrict__ cs2,
                                              float* __restrict__ diffs) {
#pragma clang fp contract(off)
  int p = blockIdx.x * 64 + threadIdx.x;
  if (p >= NPOS) return;
  if (p == 0 || p == NPOS - 1) { diffs[p] = 1e10f; return; }
  const float4* am4 = (const float4*)(cs1 + (size_t)(p - 1) * 256);
  const float4* ap4 = (const float4*)(cs1 + (size_t)(p + 1) * 256);
  const float4* bm4 = (const float4*)(cs2 + (size_t)(p - 1) * 256);
  const float4* bp4 = (const float4*)(cs2 + (size_t)(p + 1) * 256);
  float blk[2];
  for (int half = 0; half < 2; ++half) {
    float r[8];
    for (int i = 0; i < 16; ++i) {
      int q = half * 32 + i * 2;
      float4 a0 = ap4[q], m0 = am4[q], b0 = bp4[q], n0 = bm4[q];
      float4 a1 = ap4[q + 1], m1 = am4[q + 1], b1 = bp4[q + 1], n1 = bm4[q + 1];
      float e0 = dterm(a0.x, m0.x, b0.x, n0.x);
      float e1 = dterm(a0.y, m0.y, b0.y, n0.y);
      float e2 = dterm(a0.z, m0.z, b0.z, n0.z);
      float e3 = dterm(a0.w, m0.w, b0.w, n0.w);
      float e4 = dterm(a1.x, m1.x, b1.x, n1.x);
      float e5 = dterm(a1.y, m1.y, b1.y, n1.y);
      float e6 = dterm(a1.z, m1.z, b1.z, n1.z);
      float e7 = dterm(a1.w, m1.w, b1.w, n1.w);
      if (i == 0) {
        r[0] = e0; r[1] = e1; r[2] = e2; r[3] = e3;
        r[4] = e4; r[5] = e5; r[6] = e6; r[7] = e7;
      } else {
        r[0] += e0; r[1] += e1; r[2] += e2; r[3] += e3;
        r[4] += e4; r[5] += e5; r[6] += e6; r[7] += e7;
      }
    }
    blk[half] = ((r[0] + r[1]) + (r[2] + r[3])) + ((r[4] + r[5]) + (r[6] + r[7]));
  }
  float mean = (blk[0] + blk[1]) / 256.0f;
  float mx = mean > 0.0f ? mean : 0.0f;
  diffs[p] = (float)::sqrt((double)mx);
}

// --------------------------- C: radix select -------------------------------
__global__ void k_hist1(const float* __restrict__ diffs, unsigned* __restrict__ h1) {
  int p = blockIdx.x * 256 + threadIdx.x;
  if (p >= NPOS) return;
  unsigned key = __float_as_uint(diffs[p]);
  atomicAdd(&h1[key >> 16], 1u);
}

__global__ void k_sel_hi(const unsigned* __restrict__ h1, unsigned* __restrict__ meta) {
  __shared__ unsigned loc[256];
  int t = threadIdx.x;
  unsigned s = 0;
  for (int i = 0; i < 256; ++i) s += h1[t * 256 + i];
  loc[t] = s;
  __syncthreads();
  if (t == 0) {
    unsigned run = 0; int tt = 255;
    for (; tt > 0; --tt) { if (run + loc[tt] >= KSEL) break; run += loc[tt]; }
    unsigned r2 = run;
    for (int i = 255; i >= 0; --i) {
      unsigned c = h1[tt * 256 + i];
      if (r2 + c >= KSEL) { meta[0] = (unsigned)(tt * 256 + i); meta[1] = r2; break; }
      r2 += c;
    }
  }
}

__global__ void k_hist2(const float* __restrict__ diffs, const unsigned* __restrict__ meta,
                        unsigned* __restrict__ h2) {
  int p = blockIdx.x * 256 + threadIdx.x;
  if (p >= NPOS) return;
  unsigned key = __float_as_uint(diffs[p]);
  if ((key >> 16) == meta[0]) atomicAdd(&h2[key & 0xffffu], 1u);
}

__global__ void k_sel_lo(const unsigned* __restrict__ h2, unsigned* __restrict__ meta) {
  __shared__ unsigned loc[256];
  int t = threadIdx.x;
  unsigned s = 0;
  for (int i = 0; i < 256; ++i) s += h2[t * 256 + i];
  loc[t] = s;
  __syncthreads();
  if (t == 0) {
    unsigned remaining = KSEL - meta[1];
    unsigned run = 0; int tt = 255;
    for (; tt > 0; --tt) { if (run + loc[tt] >= remaining) break; run += loc[tt]; }
    unsigned r2 = run;
    for (int i = 255; i >= 0; --i) {
      unsigned c = h2[tt * 256 + i];
      if (r2 + c >= remaining) {
        meta[2] = (meta[0] << 16) | (unsigned)(tt * 256 + i);
        meta[3] = remaining - r2;
        break;
      }
      r2 += c;
    }
  }
}

// --------------------------- D: keep flags ---------------------------------
__global__ __launch_bounds__(64) void k_keep(const float* __restrict__ diffs,
                                             const unsigned* __restrict__ meta,
                                             unsigned char* __restrict__ keep) {
  int lane = threadIdx.x;
  unsigned Kstar = meta[2], need = meta[3];
  unsigned base = 0;
  float v[4], nv[4];
#pragma unroll
  for (int q = 0; q < 4; ++q) nv[q] = diffs[q * 64 + lane];
  for (int it = 0; it < 257; ++it) {
#pragma unroll
    for (int q = 0; q < 4; ++q) v[q] = nv[q];
    if (it < 256) {
      int nb = (it + 1) * 256;
#pragma unroll
      for (int q = 0; q < 4; ++q) {
        int idx = nb + q * 64 + lane;
        nv[q] = (idx < NPOS) ? diffs[idx] : 0.f;
      }
    }
#pragma unroll
    for (int q = 0; q < 4; ++q) {
      int p = it * 256 + q * 64 + lane;
      bool valid = p < NPOS;
      unsigned key = valid ? __float_as_uint(v[q]) : 0u;
      bool eq = valid && (key == Kstar);
      unsigned long long m = __ballot(eq);
      unsigned rank = base + (unsigned)__popcll(m & ((1ull << lane) - 1ull));
      bool k = valid && ((key > Kstar) || (eq && rank < need) || ((p & 1023) == 0));
      if (valid) keep[p] = (unsigned char)k;
      base += (unsigned)__popcll(m);
    }
  }
}

// --------------------------- E: per-batch segments -------------------------
__global__ __launch_bounds__(1024) void k_segment(const unsigned char* __restrict__ keep,
                                                  int* __restrict__ segid,
                                                  int* __restrict__ bnd,
                                                  int* __restrict__ nseg) {
  __shared__ int s[1024];
  int b = blockIdx.x, t = threadIdx.x;
  int f = (t >= 1) ? (int)keep[b * 1024 + t] : 0;
  s[t] = f;
  __syncthreads();
  for (int off = 1; off < 1024; off <<= 1) {
    int v = s[t];
    int add = (t >= off) ? s[t - off] : 0;
    __syncthreads();
    s[t] = v + add;
    __syncthreads();
  }
  int sc = s[t];
  segid[b * 1024 + t] = sc;
  if (f) bnd[b * 1026 + sc] = t;
  if (t == 0) bnd[b * 1026] = 0;
  if (t == 1023) {
    int m = sc + 1;
    nseg[b] = m;
    bnd[b * 1026 + m] = 1024;
  }
}

__global__ __launch_bounds__(64) void k_prefix(const int* __restrict__ nseg,
                                               int* __restrict__ pref) {
  int lane = threadIdx.x;
  int s = nseg[lane];
  for (int off = 1; off < 64; off <<= 1) {
    int u = __shfl_up(s, off);
    if (lane >= off) s += u;
  }
  pref[lane + 1] = s;
  if (lane == 0) pref[0] = 0;
}

// --------------------------- G: segment means ------------------------------
__global__ __launch_bounds__(256) void k_pool(const float* __restrict__ x,
                                              const int* __restrict__ bnd,
                                              const int* __restrict__ nseg,
                                              const int* __restrict__ pref,
                                              float* __restrict__ comp) {
  int d = threadIdx.x;
  for (int s = 0; s < 32; ++s) {
    int sid = blockIdx.x * 32 + s;
    int b = sid >> 10, li = sid & 1023;
    if (li >= nseg[b]) continue;
    int s0 = bnd[b * 1026 + li], e0 = bnd[b * 1026 + li + 1];
    float acc = 0.f;
    for (int t = s0; t < e0; ++t) acc += x[((size_t)b * 1024 + t) * 256 + d];
    comp[((size_t)pref[b] + li) * 256 + d] = acc / (float)(e0 - s0);
  }
}

// --------------------------- H: gi GEMM (fp32) -----------------------------
__global__ __launch_bounds__(256) void k_gi(const float* __restrict__ comp,
                                            const float* __restrict__ Wih,
                                            const float* __restrict__ bih,
                                            const float* __restrict__ bhh,
                                            const int* __restrict__ pref,
                                            float* __restrict__ gi) {
  int total = pref[64];
  int r0 = blockIdx.x * 64;
  if (r0 >= total) return;
  int c0 = blockIdx.y * 128;
  __shared__ float As[64][64];
  __shared__ float Bs[64 * 132];
  int tid = threadIdx.x;
  int rg = tid >> 5, cl = tid & 31;
  float acc[8][4];
#pragma unroll
  for (int i = 0; i < 8; ++i)
#pragma unroll
    for (int q = 0; q < 4; ++q) acc[i][q] = 0.f;

  for (int k0 = 0; k0 < 256; k0 += 64) {
#pragma unroll
    for (int i = 0; i < 4; ++i) {
      int idx = tid + i * 256;
      int row = idx >> 4, kq = idx & 15;
      int rr = r0 + row;
      float4 v;
      if (rr < total) v = *reinterpret_cast<const float4*>(comp + (size_t)rr * 256 + k0 + kq * 4);
      else { v.x = 0.f; v.y = 0.f; v.z = 0.f; v.w = 0.f; }
      *reinterpret_cast<float4*>(&As[row][kq * 4]) = v;
    }
#pragma unroll
    for (int i = 0; i < 8; ++i) {
      int idx = tid + i * 256;
      int row = idx >> 4, kq = idx & 15;
      float4 v = *reinterpret_cast<const float4*>(Wih + (size_t)(c0 + row) * 256 + k0 + kq * 4);
      Bs[(kq * 4 + 0) * 132 + row] = v.x;
      Bs[(kq * 4 + 1) * 132 + row] = v.y;
      Bs[(kq * 4 + 2) * 132 + row] = v.z;
      Bs[(kq * 4 + 3) * 132 + row] = v.w;
    }
    __syncthreads();
#pragma unroll 4
    for (int k = 0; k < 64; ++k) {
      float a[8], bv[4];
#pragma unroll
      for (int i = 0; i < 8; ++i) a[i] = As[rg * 8 + i][k];
#pragma unroll
      for (int q = 0; q < 4; ++q) bv[q] = Bs[k * 132 + cl + 32 * q];
#pragma unroll
      for (int i = 0; i < 8; ++i)
#pragma unroll
        for (int q = 0; q < 4; ++q) acc[i][q] += a[i] * bv[q];
    }
    __syncthreads();
  }
#pragma unroll
  for (int q = 0; q < 4; ++q) {
    int c = c0 + cl + 32 * q;
    float bias = bih[c] + (c < 512 ? bhh[c] : 0.f);
#pragma unroll
    for (int i = 0; i < 8; ++i) {
      int rr = r0 + rg * 8 + i;
      if (rr < total) gi[(size_t)rr * 768 + c] = acc[i][q] + bias;
    }
  }
}

// --------------------------- I: GRU ----------------------------------------
// 64 blocks x 512 threads (8 waves, 2 waves/SIMD -> 256 regs total/wave).
// Thread (pr = t&255, half = t>>8) owns gate rows {pr, 256+pr, 512+pr}
// restricted to k-half: wr[64] f16x2 in VGPRs; wz/wn (128 regs) pinned in
// AGPRs via explicit v_accvgpr_write/read (1-cyc VALU) -- hipcc never
// voluntarily uses the AGPR half and memory-spilled every over-cap design
// (proven by WRITE_SIZE +17-24MB across 5 attempts). h (f16) read as
// wave-uniform ds_read_b128; partials via LDS float2; raw s_barrier sync
// (no vmcnt drain) so gout stores + gi prefetch stay in flight.
__global__ __launch_bounds__(512, 1) void k_gru(const float* __restrict__ gi,
                                                const float* __restrict__ Whh,
                                                const float* __restrict__ bhh,
                                                const int* __restrict__ nseg,
                                                const int* __restrict__ pref,
                                                float* __restrict__ gout) {
  const int b = blockIdx.x;
  const int t = threadIdx.x;
  const int m = nseg[b];
  const size_t base = (size_t)pref[b];
  const int half = t >> 8;                 // wave-uniform (waves 0-3 / 4-7)
  const int pr = t & 255;
  const int k0 = half * 128;

  f16x2 wr[64];                            // r-gate weights: VGPRs
  unsigned wza[64], wna[64];               // z/n-gate weights: AGPRs
#pragma unroll
  for (int i = 0; i < 32; ++i) {
    float4 v = *(const float4*)(Whh + (size_t)pr * 256 + k0 + i * 4);
    f16x2 ra; ra.x = (_Float16)v.x; ra.y = (_Float16)v.y; wr[2 * i] = ra;
    f16x2 rb; rb.x = (_Float16)v.z; rb.y = (_Float16)v.w; wr[2 * i + 1] = rb;
    float4 u = *(const float4*)(Whh + (size_t)(256 + pr) * 256 + k0 + i * 4);
    unsigned z0 = pack_f16x2(u.x, u.y);
    unsigned z1 = pack_f16x2(u.z, u.w);
    asm("v_accvgpr_write_b32 %0, %1" : "=a"(wza[2 * i]) : "v"(z0));
    asm("v_accvgpr_write_b32 %0, %1" : "=a"(wza[2 * i + 1]) : "v"(z1));
    float4 q = *(const float4*)(Whh + (size_t)(512 + pr) * 256 + k0 + i * 4);
    unsigned n0 = pack_f16x2(q.x, q.y);
    unsigned n1 = pack_f16x2(q.z, q.w);
    asm("v_accvgpr_write_b32 %0, %1" : "=a"(wna[2 * i]) : "v"(n0));
    asm("v_accvgpr_write_b32 %0, %1" : "=a"(wna[2 * i + 1]) : "v"(n1));
  }

  __shared__ f16x8 hbuf8[32];     // h as f16 (256 vals); [half*16+i] uniform
  __shared__ float2 pp2[768];     // per-row {half0, half1} partials

  float bn = (t < 256) ? bhh[512 + t] : 0.f;
  float hreg = 0.f;               // finish thread t<256 owns h[t] in f32
  if (t < 32) {
    f16x8 z = (f16x8)(_Float16)0.f;
    hbuf8[t] = z;
  }
  __syncthreads();

  float cr = 0.f, cz = 0.f, cn = 0.f;
  if (t < 256) {
    const float* g0 = gi + base * 768;
    cr = g0[t]; cz = g0[256 + t]; cn = g0[512 + t];
  }

  for (int l = 0; l < m; ++l) {
    float nr = 0.f, nz = 0.f, nn = 0.f;
    if (t < 256 && l + 1 < m) {            // prefetch next step's gi
      const float* g1 = gi + (base + l + 1) * 768;
      nr = g1[t]; nz = g1[256 + t]; nn = g1[512 + t];
    }
    float ar0 = 0.f, ar1 = 0.f, az0 = 0.f, az1 = 0.f, an0 = 0.f, an1 = 0.f;
#pragma unroll
    for (int i = 0; i < 16; ++i) {
      f16x8 hv = hbuf8[half * 16 + i];     // uniform ds_read_b128
      f16x2 p0; p0.x = hv[0]; p0.y = hv[1];
      f16x2 p1; p1.x = hv[2]; p1.y = hv[3];
      f16x2 p2; p2.x = hv[4]; p2.y = hv[5];
      f16x2 p3; p3.x = hv[6]; p3.y = hv[7];
      ar0 = fdot2f(wr[4 * i + 0], p0, ar0);
      ar1 = fdot2f(wr[4 * i + 1], p1, ar1);
      ar0 = fdot2f(wr[4 * i + 2], p2, ar0);
      ar1 = fdot2f(wr[4 * i + 3], p3, ar1);
      unsigned tz0, tz1, tz2, tz3;
      asm("v_accvgpr_read_b32 %0, %1" : "=v"(tz0) : "a"(wza[4 * i + 0]));
      asm("v_accvgpr_read_b32 %0, %1" : "=v"(tz1) : "a"(wza[4 * i + 1]));
      asm("v_accvgpr_read_b32 %0, %1" : "=v"(tz2) : "a"(wza[4 * i + 2]));
      asm("v_accvgpr_read_b32 %0, %1" : "=v"(tz3) : "a"(wza[4 * i + 3]));
      az0 = fdot2f(as_f16x2(tz0), p0, az0);
      az1 = fdot2f(as_f16x2(tz1), p1, az1);
      az0 = fdot2f(as_f16x2(tz2), p2, az0);
      az1 = fdot2f(as_f16x2(tz3), p3, az1);
      unsigned tn0, tn1, tn2, tn3;
      asm("v_accvgpr_read_b32 %0, %1" : "=v"(tn0) : "a"(wna[4 * i + 0]));
      asm("v_accvgpr_read_b32 %0, %1" : "=v"(tn1) : "a"(wna[4 * i + 1]));
      asm("v_accvgpr_read_b32 %0, %1" : "=v"(tn2) : "a"(wna[4 * i + 2]));
      asm("v_accvgpr_read_b32 %0, %1" : "=v"(tn3) : "a"(wna[4 * i + 3]));
      an0 = fdot2f(as_f16x2(tn0), p0, an0);
      an1 = fdot2f(as_f16x2(tn1), p1, an1);
      an0 = fdot2f(as_f16x2(tn2), p2, an0);
      an1 = fdot2f(as_f16x2(tn3), p3, an1);
    }
    float* ppf = (float*)pp2;
    ppf[pr * 2 + half] = ar0 + ar1;
    ppf[(256 + pr) * 2 + half] = az0 + az1;
    ppf[(512 + pr) * 2 + half] = an0 + an1;
    asm volatile("s_waitcnt lgkmcnt(0)" ::: "memory");
    __builtin_amdgcn_sched_barrier(0);
    __builtin_amdgcn_s_barrier();
    __builtin_amdgcn_sched_barrier(0);
    if (t < 256) {
      float2 qr = pp2[t];
      float2 qz = pp2[256 + t];
      float2 qn = pp2[512 + t];
      float sr = qr.x + qr.y;
      float sz = qz.x + qz.y;
      float sn = qn.x + qn.y + bn;
      float r = 1.f / (1.f + __expf(-(cr + sr)));
      float z = 1.f / (1.f + __expf(-(cz + sz)));
      float arg = cn + r * sn;
      float n = 2.f / (1.f + __expf(-2.f * arg)) - 1.f;   // tanh
      float hnew = (1.f - z) * n + z * hreg;
      hreg = hnew;
      ((_Float16*)hbuf8)[t] = (_Float16)hnew;
      gout[(base + l) * 256 + t] = hnew;
    }
    cr = nr; cz = nz; cn = nn;
    asm volatile("s_waitcnt lgkmcnt(0)" ::: "memory");
    __builtin_amdgcn_sched_barrier(0);
    __builtin_amdgcn_s_barrier();
    __builtin_amdgcn_sched_barrier(0);
  }
}

// --------------------------- J: scatter ------------------------------------
__global__ __launch_bounds__(256) void k_scatter(const float* __restrict__ gout,
                                                 const int* __restrict__ segid,
                                                 const int* __restrict__ pref,
                                                 float* __restrict__ out) {
  int d = threadIdx.x;
  for (int rr = 0; rr < 32; ++rr) {
    int row = blockIdx.x * 32 + rr;
    int b = row >> 10;
    int l = segid[row];
    out[(size_t)row * 256 + d] = gout[((size_t)pref[b] + l) * 256 + d];
  }
}

// ---------------------------------------------------------------------------
extern "C" void kernel_launch(void* const* d_in, const int* in_sizes, int n_in,
                              void* d_out, int out_size, void* d_ws, size_t ws_size,
                              hipStream_t stream) {
  const float* x   = (const float*)d_in[0];
  const float* Wih = (const float*)d_in[1];
  const float* Whh = (const float*)d_in[2];
  const float* bih = (const float*)d_in[3];
  const float* bhh = (const float*)d_in[4];
  float* out = (float*)d_out;
  char* w = (char*)d_ws;

  const size_t o_cs1   = 0;
  const size_t o_cs2   = 67110912;
  const size_t o_diffs = 134221824;
  const size_t o_h1    = 134484224;
  const size_t o_h2    = 134746368;
  const size_t o_meta  = 135008512;
  const size_t o_keep  = 135008768;
  const size_t o_segid = 135074560;
  const size_t o_bnd   = 135336704;
  const size_t o_nseg  = 135599360;
  const size_t o_pref  = 135599616;
  const size_t o_gi    = 135600128;
  const size_t NEED    = 236460032;
  if (ws_size < NEED) return;

  float* cs1 = (float*)(w + o_cs1);
  float* cs2 = (float*)(w + o_cs2);
  float* diffs = (float*)(w + o_diffs);
  unsigned* h1 = (unsigned*)(w + o_h1);
  unsigned* h2 = (unsigned*)(w + o_h2);
  unsigned* meta = (unsigned*)(w + o_meta);
  unsigned char* keep = (unsigned char*)(w + o_keep);
  int* segid = (int*)(w + o_segid);
  int* bnd = (int*)(w + o_bnd);
  int* nseg = (int*)(w + o_nseg);
  int* pref = (int*)(w + o_pref);
  float* gi = (float*)(w + o_gi);
  float* carr = (float*)(w + o_gi);   // 524,288 B; dead before k_gi writes gi
  float* comp = cs1;                  // reuse (cs1 dead after k_diffs)
  float* gout = cs2;                  // reuse
  float* sink = (float*)(w + o_meta + 192);

  hipMemsetAsync(h1, 0, 262144, stream);
  hipMemsetAsync(h2, 0, 262144, stream);

  k_warm   <<<dim3(16384),  dim3(256),  0, stream>>>((const float4*)x, sink);
  k_carry  <<<dim3(8),      dim3(256),  0, stream>>>(x, carr);
  k_spread <<<dim3(512),    dim3(256),  0, stream>>>(x, carr, cs1, cs2);
  k_diffs  <<<dim3(1025),   dim3(64),   0, stream>>>(cs1, cs2, diffs);
  k_hist1  <<<dim3(257),    dim3(256),  0, stream>>>(diffs, h1);
  k_sel_hi <<<dim3(1),      dim3(256),  0, stream>>>(h1, meta);
  k_hist2  <<<dim3(257),    dim3(256),  0, stream>>>(diffs, meta, h2);
  k_sel_lo <<<dim3(1),      dim3(256),  0, stream>>>(h2, meta);
  k_keep   <<<dim3(1),      dim3(64),   0, stream>>>(diffs, meta, keep);
  k_segment<<<dim3(64),     dim3(1024), 0, stream>>>(keep, segid, bnd, nseg);
  k_prefix <<<dim3(1),      dim3(64),   0, stream>>>(nseg, pref);
  k_pool   <<<dim3(2048),   dim3(256),  0, stream>>>(x, bnd, nseg, pref, comp);
  k_gi     <<<dim3(513, 6), dim3(256),  0, stream>>>(comp, Wih, bih, bhh, pref, gi);
  k_gru    <<<dim3(64),     dim3(512),  0, stream>>>(gi, Whh, bhh, nseg, pref, gout);
  k_scatter<<<dim3(2048),   dim3(256),  0, stream>>>(gout, segid, pref, out);
}

// Round 12
// 1906.126 us; speedup vs baseline: 1.5818x; 1.5818x over previous
//
#include <hip/hip_runtime.h>
#include <cstdint>
#include <cstddef>
#include <cmath>

// ---------------------------------------------------------------------------
// Pipeline:
//   A0 k_warm   : pull x into L2/L3 (full-GPU streaming read, ~13us)
//   A1 k_carry  : exact sequential fl cumsum chains (8 blocks producer-
//                 consumer LDS double-buffer), 256-row checkpoints only
//   A2 k_spread : 512 blocks replay each 256-row chunk from its exact carry
//   B  k_diffs  : exact numpy-pairwise variance->diffs (float4 loads)
//   C  k_hist1/k_sel_hi/k_hist2/k_sel_lo : exact top-32768 radix select
//   D  k_keep   : keep flags, stable tie ranks
//   E  k_segment: per-batch boundary lists + frame->segment map
//   F  k_prefix : ragged row offsets
//   G  k_pool   : segment means (comp)
//   H  k_gi     : gi = comp @ W_ih^T + biases  [fp32 GEMM]
//   I  k_gru    : sequential GRU, 512 thr. Allocator law (6 data points):
//                 hipcc budgets for 2 blocks/CU -> per-wave cap =
//                 512/(2 x block-waves-per-SIMD); launch_bounds arg2 is
//                 IGNORED for budgeting. amdgpu_waves_per_eu(2,2) pins
//                 2 waves/EU -> 256-reg budget -> the 192 f16x2 weight
//                 arrays fit register-resident with NO spill and NO asm.
//                 (AGPR inline-asm variant: spill gone but reads serialize,
//                 1805us -- reverted.)
//   J  k_scatter: out[b,t,:] = gru_out[b, seg(t), :]
// ---------------------------------------------------------------------------

#define NPOS 65537
#define KSEL 32768u

typedef _Float16 f16x2 __attribute__((ext_vector_type(2)));
typedef _Float16 f16x8 __attribute__((ext_vector_type(8)));

#if defined(__has_builtin)
#if __has_builtin(__builtin_amdgcn_fdot2)
#define HAVE_FDOT2 1
#endif
#endif

__device__ __forceinline__ float fdot2f(f16x2 a, f16x2 b, float c) {
#ifdef HAVE_FDOT2
  return __builtin_amdgcn_fdot2(a, b, c, false);
#else
  c += (float)a.x * (float)b.x;
  c += (float)a.y * (float)b.y;
  return c;
#endif
}

// --------------------------- A0: warm x into cache -------------------------
__global__ __launch_bounds__(256) void k_warm(const float4* __restrict__ x4,
                                              float* __restrict__ sink) {
  size_t i = (size_t)blockIdx.x * 256 + threadIdx.x;
  float4 v = x4[i];
  float s = (v.x + v.y) + (v.z + v.w);
  if (s == 1.23456789e-33f) sink[0] = s;  // deterministically false; keeps loads
}

// --------------------------- A1: carry chains ------------------------------
__global__ __launch_bounds__(256) void k_carry(const float* __restrict__ x,
                                               float* __restrict__ carr) {
  __shared__ __align__(16) float lds[2 * 256 * 64];   // 128 KiB
  const int b = blockIdx.x;
  const int sq = b >> 2;
  const int j0 = (b & 3) * 64;
  const int wid = threadIdx.x >> 6;
  const int l = threadIdx.x & 63;

  if (wid != 0) {
    // ----- stagers -----
    const int wsel = wid - 1;   // 0..2; handles 4-row groups g with g%3==wsel
    const size_t lane_off = (size_t)(l >> 4) * 256 + (size_t)(l & 15) * 4;
    for (int c = 0; c <= 256; ++c) {
      if (c < 256) {
        const float* src = x + (size_t)c * 256 * 256 + j0 + lane_off;
        float* dbase = lds + (c & 1) * 16384;
        for (int g = wsel; g < 64; g += 3) {
          __builtin_amdgcn_global_load_lds(
              (const __attribute__((address_space(1))) void*)(src + (size_t)g * 1024),
              (__attribute__((address_space(3))) void*)(dbase + g * 256),
              16, 0, 0);
        }
      }
      asm volatile("s_waitcnt vmcnt(0)" ::: "memory");
      __builtin_amdgcn_sched_barrier(0);
      __builtin_amdgcn_s_barrier();
      __builtin_amdgcn_sched_barrier(0);
    }
  } else {
    // ----- chain wave -----
#pragma clang fp contract(off)
    __builtin_amdgcn_s_barrier();        // chunk 0 staged
    __builtin_amdgcn_sched_barrier(0);
    float acc = 0.f;
    float* cw = carr + ((size_t)sq * 256) * 256 + j0 + l;
    if (sq) {
      for (int c = 0; c < 256; ++c) {
        cw[(size_t)c * 256] = acc;       // carry BEFORE chunk c's rows
        const float* lp = lds + (c & 1) * 16384 + l;
#pragma unroll 16
        for (int r = 0; r < 256; ++r) {
          float v = lp[r * 64];
          v = v * v;                     // rounded square, then add (no FMA)
          acc = acc + v;
        }
        asm volatile("s_waitcnt lgkmcnt(0)" ::: "memory");
        __builtin_amdgcn_sched_barrier(0);
        __builtin_amdgcn_s_barrier();
        __builtin_amdgcn_sched_barrier(0);
      }
    } else {
      for (int c = 0; c < 256; ++c) {
        cw[(size_t)c * 256] = acc;
        const float* lp = lds + (c & 1) * 16384 + l;
#pragma unroll 16
        for (int r = 0; r < 256; ++r) {
          float v = lp[r * 64];
          acc = acc + v;
        }
        asm volatile("s_waitcnt lgkmcnt(0)" ::: "memory");
        __builtin_amdgcn_sched_barrier(0);
        __builtin_amdgcn_s_barrier();
        __builtin_amdgcn_sched_barrier(0);
      }
    }
  }
}

// --------------------------- A2: spread chunks -----------------------------
__global__ __launch_bounds__(256) void k_spread(const float* __restrict__ x,
                                                const float* __restrict__ carr,
                                                float* __restrict__ cs1,
                                                float* __restrict__ cs2) {
#pragma clang fp contract(off)
  const int blk = blockIdx.x;
  const int sq = blk >> 8;
  const int ch = blk & 255;
  const int col = threadIdx.x;
  float* dst = sq ? cs2 : cs1;
  float c = carr[((size_t)sq * 256 + ch) * 256 + col];
  const float* gp = x + (size_t)ch * 256 * 256 + col;
  float* sp = dst + ((size_t)ch * 256 + 1) * 256 + col;
  if (ch == 0) dst[col] = 0.f;        // p=0 row (enc zero prepend)
  float buf[4][8];
#pragma unroll
  for (int d = 0; d < 3; ++d)
#pragma unroll
    for (int u = 0; u < 8; ++u)
      buf[d][u] = gp[(size_t)(d * 8 + u) * 256];
  for (int g = 0; g < 8; ++g) {
#pragma unroll
    for (int d = 0; d < 4; ++d) {
      const int s = g * 4 + d;        // 8-row group (0..31)
      if (s + 3 < 32) {
        const float* ld = gp + (size_t)(s + 3) * 8 * 256;
#pragma unroll
        for (int u = 0; u < 8; ++u)
          buf[(d + 3) & 3][u] = ld[(size_t)u * 256];
      }
#pragma unroll
      for (int u = 0; u < 8; ++u) {
        float v = buf[d][u];
        if (sq) v = v * v;
        c = c + v;
        sp[(size_t)(s * 8 + u) * 256] = c;
      }
    }
  }
}

// --------------------------- B: exact diffs --------------------------------
__device__ __forceinline__ float dterm(float ap, float am, float bp, float bm) {
#pragma clang fp contract(off)
  float s1 = ap - am;
  float s2 = bp - bm;
  float t1 = s1 * 0.5f;
  float u = s2 * 0.5f;
  return u - t1 * t1;
}

__global__ __launch_bounds__(64) void k_diffs(const float* __restrict__ cs1,
                                              const float* __restrict__ cs2,
                                              float* __restrict__ diffs) {
#pragma clang fp contract(off)
  int p = blockIdx.x * 64 + threadIdx.x;
  if (p >= NPOS) return;
  if (p == 0 || p == NPOS - 1) { diffs[p] = 1e10f; return; }
  const float4* am4 = (const float4*)(cs1 + (size_t)(p - 1) * 256);
  const float4* ap4 = (const float4*)(cs1 + (size_t)(p + 1) * 256);
  const float4* bm4 = (const float4*)(cs2 + (size_t)(p - 1) * 256);
  const float4* bp4 = (const float4*)(cs2 + (size_t)(p + 1) * 256);
  float blk[2];
  for (int half = 0; half < 2; ++half) {
    float r[8];
    for (int i = 0; i < 16; ++i) {
      int q = half * 32 + i * 2;
      float4 a0 = ap4[q], m0 = am4[q], b0 = bp4[q], n0 = bm4[q];
      float4 a1 = ap4[q + 1], m1 = am4[q + 1], b1 = bp4[q + 1], n1 = bm4[q + 1];
      float e0 = dterm(a0.x, m0.x, b0.x, n0.x);
      float e1 = dterm(a0.y, m0.y, b0.y, n0.y);
      float e2 = dterm(a0.z, m0.z, b0.z, n0.z);
      float e3 = dterm(a0.w, m0.w, b0.w, n0.w);
      float e4 = dterm(a1.x, m1.x, b1.x, n1.x);
      float e5 = dterm(a1.y, m1.y, b1.y, n1.y);
      float e6 = dterm(a1.z, m1.z, b1.z, n1.z);
      float e7 = dterm(a1.w, m1.w, b1.w, n1.w);
      if (i == 0) {
        r[0] = e0; r[1] = e1; r[2] = e2; r[3] = e3;
        r[4] = e4; r[5] = e5; r[6] = e6; r[7] = e7;
      } else {
        r[0] += e0; r[1] += e1; r[2] += e2; r[3] += e3;
        r[4] += e4; r[5] += e5; r[6] += e6; r[7] += e7;
      }
    }
    blk[half] = ((r[0] + r[1]) + (r[2] + r[3])) + ((r[4] + r[5]) + (r[6] + r[7]));
  }
  float mean = (blk[0] + blk[1]) / 256.0f;
  float mx = mean > 0.0f ? mean : 0.0f;
  diffs[p] = (float)::sqrt((double)mx);
}

// --------------------------- C: radix select -------------------------------
__global__ void k_hist1(const float* __restrict__ diffs, unsigned* __restrict__ h1) {
  int p = blockIdx.x * 256 + threadIdx.x;
  if (p >= NPOS) return;
  unsigned key = __float_as_uint(diffs[p]);
  atomicAdd(&h1[key >> 16], 1u);
}

__global__ void k_sel_hi(const unsigned* __restrict__ h1, unsigned* __restrict__ meta) {
  __shared__ unsigned loc[256];
  int t = threadIdx.x;
  unsigned s = 0;
  for (int i = 0; i < 256; ++i) s += h1[t * 256 + i];
  loc[t] = s;
  __syncthreads();
  if (t == 0) {
    unsigned run = 0; int tt = 255;
    for (; tt > 0; --tt) { if (run + loc[tt] >= KSEL) break; run += loc[tt]; }
    unsigned r2 = run;
    for (int i = 255; i >= 0; --i) {
      unsigned c = h1[tt * 256 + i];
      if (r2 + c >= KSEL) { meta[0] = (unsigned)(tt * 256 + i); meta[1] = r2; break; }
      r2 += c;
    }
  }
}

__global__ void k_hist2(const float* __restrict__ diffs, const unsigned* __restrict__ meta,
                        unsigned* __restrict__ h2) {
  int p = blockIdx.x * 256 + threadIdx.x;
  if (p >= NPOS) return;
  unsigned key = __float_as_uint(diffs[p]);
  if ((key >> 16) == meta[0]) atomicAdd(&h2[key & 0xffffu], 1u);
}

__global__ void k_sel_lo(const unsigned* __restrict__ h2, unsigned* __restrict__ meta) {
  __shared__ unsigned loc[256];
  int t = threadIdx.x;
  unsigned s = 0;
  for (int i = 0; i < 256; ++i) s += h2[t * 256 + i];
  loc[t] = s;
  __syncthreads();
  if (t == 0) {
    unsigned remaining = KSEL - meta[1];
    unsigned run = 0; int tt = 255;
    for (; tt > 0; --tt) { if (run + loc[tt] >= remaining) break; run += loc[tt]; }
    unsigned r2 = run;
    for (int i = 255; i >= 0; --i) {
      unsigned c = h2[tt * 256 + i];
      if (r2 + c >= remaining) {
        meta[2] = (meta[0] << 16) | (unsigned)(tt * 256 + i);
        meta[3] = remaining - r2;
        break;
      }
      r2 += c;
    }
  }
}

// --------------------------- D: keep flags ---------------------------------
__global__ __launch_bounds__(64) void k_keep(const float* __restrict__ diffs,
                                             const unsigned* __restrict__ meta,
                                             unsigned char* __restrict__ keep) {
  int lane = threadIdx.x;
  unsigned Kstar = meta[2], need = meta[3];
  unsigned base = 0;
  float v[4], nv[4];
#pragma unroll
  for (int q = 0; q < 4; ++q) nv[q] = diffs[q * 64 + lane];
  for (int it = 0; it < 257; ++it) {
#pragma unroll
    for (int q = 0; q < 4; ++q) v[q] = nv[q];
    if (it < 256) {
      int nb = (it + 1) * 256;
#pragma unroll
      for (int q = 0; q < 4; ++q) {
        int idx = nb + q * 64 + lane;
        nv[q] = (idx < NPOS) ? diffs[idx] : 0.f;
      }
    }
#pragma unroll
    for (int q = 0; q < 4; ++q) {
      int p = it * 256 + q * 64 + lane;
      bool valid = p < NPOS;
      unsigned key = valid ? __float_as_uint(v[q]) : 0u;
      bool eq = valid && (key == Kstar);
      unsigned long long m = __ballot(eq);
      unsigned rank = base + (unsigned)__popcll(m & ((1ull << lane) - 1ull));
      bool k = valid && ((key > Kstar) || (eq && rank < need) || ((p & 1023) == 0));
      if (valid) keep[p] = (unsigned char)k;
      base += (unsigned)__popcll(m);
    }
  }
}

// --------------------------- E: per-batch segments -------------------------
__global__ __launch_bounds__(1024) void k_segment(const unsigned char* __restrict__ keep,
                                                  int* __restrict__ segid,
                                                  int* __restrict__ bnd,
                                                  int* __restrict__ nseg) {
  __shared__ int s[1024];
  int b = blockIdx.x, t = threadIdx.x;
  int f = (t >= 1) ? (int)keep[b * 1024 + t] : 0;
  s[t] = f;
  __syncthreads();
  for (int off = 1; off < 1024; off <<= 1) {
    int v = s[t];
    int add = (t >= off) ? s[t - off] : 0;
    __syncthreads();
    s[t] = v + add;
    __syncthreads();
  }
  int sc = s[t];
  segid[b * 1024 + t] = sc;
  if (f) bnd[b * 1026 + sc] = t;
  if (t == 0) bnd[b * 1026] = 0;
  if (t == 1023) {
    int m = sc + 1;
    nseg[b] = m;
    bnd[b * 1026 + m] = 1024;
  }
}

__global__ __launch_bounds__(64) void k_prefix(const int* __restrict__ nseg,
                                               int* __restrict__ pref) {
  int lane = threadIdx.x;
  int s = nseg[lane];
  for (int off = 1; off < 64; off <<= 1) {
    int u = __shfl_up(s, off);
    if (lane >= off) s += u;
  }
  pref[lane + 1] = s;
  if (lane == 0) pref[0] = 0;
}

// --------------------------- G: segment means ------------------------------
__global__ __launch_bounds__(256) void k_pool(const float* __restrict__ x,
                                              const int* __restrict__ bnd,
                                              const int* __restrict__ nseg,
                                              const int* __restrict__ pref,
                                              float* __restrict__ comp) {
  int d = threadIdx.x;
  for (int s = 0; s < 32; ++s) {
    int sid = blockIdx.x * 32 + s;
    int b = sid >> 10, li = sid & 1023;
    if (li >= nseg[b]) continue;
    int s0 = bnd[b * 1026 + li], e0 = bnd[b * 1026 + li + 1];
    float acc = 0.f;
    for (int t = s0; t < e0; ++t) acc += x[((size_t)b * 1024 + t) * 256 + d];
    comp[((size_t)pref[b] + li) * 256 + d] = acc / (float)(e0 - s0);
  }
}

// --------------------------- H: gi GEMM (fp32) -----------------------------
__global__ __launch_bounds__(256) void k_gi(const float* __restrict__ comp,
                                            const float* __restrict__ Wih,
                                            const float* __restrict__ bih,
                                            const float* __restrict__ bhh,
                                            const int* __restrict__ pref,
                                            float* __restrict__ gi) {
  int total = pref[64];
  int r0 = blockIdx.x * 64;
  if (r0 >= total) return;
  int c0 = blockIdx.y * 128;
  __shared__ float As[64][64];
  __shared__ float Bs[64 * 132];
  int tid = threadIdx.x;
  int rg = tid >> 5, cl = tid & 31;
  float acc[8][4];
#pragma unroll
  for (int i = 0; i < 8; ++i)
#pragma unroll
    for (int q = 0; q < 4; ++q) acc[i][q] = 0.f;

  for (int k0 = 0; k0 < 256; k0 += 64) {
#pragma unroll
    for (int i = 0; i < 4; ++i) {
      int idx = tid + i * 256;
      int row = idx >> 4, kq = idx & 15;
      int rr = r0 + row;
      float4 v;
      if (rr < total) v = *reinterpret_cast<const float4*>(comp + (size_t)rr * 256 + k0 + kq * 4);
      else { v.x = 0.f; v.y = 0.f; v.z = 0.f; v.w = 0.f; }
      *reinterpret_cast<float4*>(&As[row][kq * 4]) = v;
    }
#pragma unroll
    for (int i = 0; i < 8; ++i) {
      int idx = tid + i * 256;
      int row = idx >> 4, kq = idx & 15;
      float4 v = *reinterpret_cast<const float4*>(Wih + (size_t)(c0 + row) * 256 + k0 + kq * 4);
      Bs[(kq * 4 + 0) * 132 + row] = v.x;
      Bs[(kq * 4 + 1) * 132 + row] = v.y;
      Bs[(kq * 4 + 2) * 132 + row] = v.z;
      Bs[(kq * 4 + 3) * 132 + row] = v.w;
    }
    __syncthreads();
#pragma unroll 4
    for (int k = 0; k < 64; ++k) {
      float a[8], bv[4];
#pragma unroll
      for (int i = 0; i < 8; ++i) a[i] = As[rg * 8 + i][k];
#pragma unroll
      for (int q = 0; q < 4; ++q) bv[q] = Bs[k * 132 + cl + 32 * q];
#pragma unroll
      for (int i = 0; i < 8; ++i)
#pragma unroll
        for (int q = 0; q < 4; ++q) acc[i][q] += a[i] * bv[q];
    }
    __syncthreads();
  }
#pragma unroll
  for (int q = 0; q < 4; ++q) {
    int c = c0 + cl + 32 * q;
    float bias = bih[c] + (c < 512 ? bhh[c] : 0.f);
#pragma unroll
    for (int i = 0; i < 8; ++i) {
      int rr = r0 + rg * 8 + i;
      if (rr < total) gi[(size_t)rr * 768 + c] = acc[i][q] + bias;
    }
  }
}

// --------------------------- I: GRU ----------------------------------------
// 64 blocks x 512 threads (8 waves, 2/SIMD). amdgpu_waves_per_eu(2,2) pins
// occupancy to 2 waves/EU -> per-wave VGPR budget 512/2 = 256 (hipcc's
// default budgets for 2 blocks/CU: cap = 512/(2 x block-waves-per-SIMD),
// which gave 128/85/64 and memory-spilled the weights in 5 prior configs;
// launch_bounds arg2 is ignored for budgeting). Thread (pr=t&255,
// half=t>>8) owns gate rows {pr, 256+pr, 512+pr} restricted to k-half:
// 192 f16x2 weights + ~35 temps ~= 227 regs, register-resident. h (f16)
// read as wave-uniform ds_read_b128. Partials via LDS float2 (2-way =
// conflict-free). Raw s_barrier sync (no vmcnt drain) so gout stores +
// gi prefetch stay in flight.
__global__ __attribute__((amdgpu_waves_per_eu(2, 2)))
__launch_bounds__(512) void k_gru(const float* __restrict__ gi,
                                  const float* __restrict__ Whh,
                                  const float* __restrict__ bhh,
                                  const int* __restrict__ nseg,
                                  const int* __restrict__ pref,
                                  float* __restrict__ gout) {
  const int b = blockIdx.x;
  const int t = threadIdx.x;
  const int m = nseg[b];
  const size_t base = (size_t)pref[b];
  const int half = t >> 8;                 // wave-uniform (waves 0-3 / 4-7)
  const int pr = t & 255;
  const int k0 = half * 128;

  f16x2 wr[64], wz[64], wn[64];            // 192 VGPRs of weights
#pragma unroll
  for (int i = 0; i < 32; ++i) {
    float4 v = *(const float4*)(Whh + (size_t)pr * 256 + k0 + i * 4);
    f16x2 ra; ra.x = (_Float16)v.x; ra.y = (_Float16)v.y; wr[2 * i] = ra;
    f16x2 rb; rb.x = (_Float16)v.z; rb.y = (_Float16)v.w; wr[2 * i + 1] = rb;
    float4 u = *(const float4*)(Whh + (size_t)(256 + pr) * 256 + k0 + i * 4);
    f16x2 za; za.x = (_Float16)u.x; za.y = (_Float16)u.y; wz[2 * i] = za;
    f16x2 zb; zb.x = (_Float16)u.z; zb.y = (_Float16)u.w; wz[2 * i + 1] = zb;
    float4 q = *(const float4*)(Whh + (size_t)(512 + pr) * 256 + k0 + i * 4);
    f16x2 na; na.x = (_Float16)q.x; na.y = (_Float16)q.y; wn[2 * i] = na;
    f16x2 nb; nb.x = (_Float16)q.z; nb.y = (_Float16)q.w; wn[2 * i + 1] = nb;
  }

  __shared__ f16x8 hbuf8[32];     // h as f16 (256 vals); [half*16+i] uniform
  __shared__ float2 pp2[768];     // per-row {half0, half1} partials

  float bn = (t < 256) ? bhh[512 + t] : 0.f;
  float hreg = 0.f;               // finish thread t<256 owns h[t] in f32
  if (t < 32) {
    f16x8 z = (f16x8)(_Float16)0.f;
    hbuf8[t] = z;
  }
  __syncthreads();

  float cr = 0.f, cz = 0.f, cn = 0.f;
  if (t < 256) {
    const float* g0 = gi + base * 768;
    cr = g0[t]; cz = g0[256 + t]; cn = g0[512 + t];
  }

  for (int l = 0; l < m; ++l) {
    float nr = 0.f, nz = 0.f, nn = 0.f;
    if (t < 256 && l + 1 < m) {            // prefetch next step's gi
      const float* g1 = gi + (base + l + 1) * 768;
      nr = g1[t]; nz = g1[256 + t]; nn = g1[512 + t];
    }
    float ar0 = 0.f, ar1 = 0.f, az0 = 0.f, az1 = 0.f, an0 = 0.f, an1 = 0.f;
#pragma unroll
    for (int i = 0; i < 16; ++i) {
      f16x8 hv = hbuf8[half * 16 + i];     // uniform ds_read_b128
      f16x2 p0; p0.x = hv[0]; p0.y = hv[1];
      f16x2 p1; p1.x = hv[2]; p1.y = hv[3];
      f16x2 p2; p2.x = hv[4]; p2.y = hv[5];
      f16x2 p3; p3.x = hv[6]; p3.y = hv[7];
      ar0 = fdot2f(wr[4 * i + 0], p0, ar0);
      ar1 = fdot2f(wr[4 * i + 1], p1, ar1);
      ar0 = fdot2f(wr[4 * i + 2], p2, ar0);
      ar1 = fdot2f(wr[4 * i + 3], p3, ar1);
      az0 = fdot2f(wz[4 * i + 0], p0, az0);
      az1 = fdot2f(wz[4 * i + 1], p1, az1);
      az0 = fdot2f(wz[4 * i + 2], p2, az0);
      az1 = fdot2f(wz[4 * i + 3], p3, az1);
      an0 = fdot2f(wn[4 * i + 0], p0, an0);
      an1 = fdot2f(wn[4 * i + 1], p1, an1);
      an0 = fdot2f(wn[4 * i + 2], p2, an0);
      an1 = fdot2f(wn[4 * i + 3], p3, an1);
    }
    float* ppf = (float*)pp2;
    ppf[pr * 2 + half] = ar0 + ar1;
    ppf[(256 + pr) * 2 + half] = az0 + az1;
    ppf[(512 + pr) * 2 + half] = an0 + an1;
    asm volatile("s_waitcnt lgkmcnt(0)" ::: "memory");
    __builtin_amdgcn_sched_barrier(0);
    __builtin_amdgcn_s_barrier();
    __builtin_amdgcn_sched_barrier(0);
    if (t < 256) {
      float2 qr = pp2[t];
      float2 qz = pp2[256 + t];
      float2 qn = pp2[512 + t];
      float sr = qr.x + qr.y;
      float sz = qz.x + qz.y;
      float sn = qn.x + qn.y + bn;
      float r = 1.f / (1.f + __expf(-(cr + sr)));
      float z = 1.f / (1.f + __expf(-(cz + sz)));
      float arg = cn + r * sn;
      float n = 2.f / (1.f + __expf(-2.f * arg)) - 1.f;   // tanh
      float hnew = (1.f - z) * n + z * hreg;
      hreg = hnew;
      ((_Float16*)hbuf8)[t] = (_Float16)hnew;
      gout[(base + l) * 256 + t] = hnew;
    }
    cr = nr; cz = nz; cn = nn;
    asm volatile("s_waitcnt lgkmcnt(0)" ::: "memory");
    __builtin_amdgcn_sched_barrier(0);
    __builtin_amdgcn_s_barrier();
    __builtin_amdgcn_sched_barrier(0);
  }
}

// --------------------------- J: scatter ------------------------------------
__global__ __launch_bounds__(256) void k_scatter(const float* __restrict__ gout,
                                                 const int* __restrict__ segid,
                                                 const int* __restrict__ pref,
                                                 float* __restrict__ out) {
  int d = threadIdx.x;
  for (int rr = 0; rr < 32; ++rr) {
    int row = blockIdx.x * 32 + rr;
    int b = row >> 10;
    int l = segid[row];
    out[(size_t)row * 256 + d] = gout[((size_t)pref[b] + l) * 256 + d];
  }
}

// ---------------------------------------------------------------------------
extern "C" void kernel_launch(void* const* d_in, const int* in_sizes, int n_in,
                              void* d_out, int out_size, void* d_ws, size_t ws_size,
                              hipStream_t stream) {
  const float* x   = (const float*)d_in[0];
  const float* Wih = (const float*)d_in[1];
  const float* Whh = (const float*)d_in[2];
  const float* bih = (const float*)d_in[3];
  const float* bhh = (const float*)d_in[4];
  float* out = (float*)d_out;
  char* w = (char*)d_ws;

  const size_t o_cs1   = 0;
  const size_t o_cs2   = 67110912;
  const size_t o_diffs = 134221824;
  const size_t o_h1    = 134484224;
  const size_t o_h2    = 134746368;
  const size_t o_meta  = 135008512;
  const size_t o_keep  = 135008768;
  const size_t o_segid = 135074560;
  const size_t o_bnd   = 135336704;
  const size_t o_nseg  = 135599360;
  const size_t o_pref  = 135599616;
  const size_t o_gi    = 135600128;
  const size_t NEED    = 236460032;
  if (ws_size < NEED) return;

  float* cs1 = (float*)(w + o_cs1);
  float* cs2 = (float*)(w + o_cs2);
  float* diffs = (float*)(w + o_diffs);
  unsigned* h1 = (unsigned*)(w + o_h1);
  unsigned* h2 = (unsigned*)(w + o_h2);
  unsigned* meta = (unsigned*)(w + o_meta);
  unsigned char* keep = (unsigned char*)(w + o_keep);
  int* segid = (int*)(w + o_segid);
  int* bnd = (int*)(w + o_bnd);
  int* nseg = (int*)(w + o_nseg);
  int* pref = (int*)(w + o_pref);
  float* gi = (float*)(w + o_gi);
  float* carr = (float*)(w + o_gi);   // 524,288 B; dead before k_gi writes gi
  float* comp = cs1;                  // reuse (cs1 dead after k_diffs)
  float* gout = cs2;                  // reuse
  float* sink = (float*)(w + o_meta + 192);

  hipMemsetAsync(h1, 0, 262144, stream);
  hipMemsetAsync(h2, 0, 262144, stream);

  k_warm   <<<dim3(16384),  dim3(256),  0, stream>>>((const float4*)x, sink);
  k_carry  <<<dim3(8),      dim3(256),  0, stream>>>(x, carr);
  k_spread <<<dim3(512),    dim3(256),  0, stream>>>(x, carr, cs1, cs2);
  k_diffs  <<<dim3(1025),   dim3(64),   0, stream>>>(cs1, cs2, diffs);
  k_hist1  <<<dim3(257),    dim3(256),  0, stream>>>(diffs, h1);
  k_sel_hi <<<dim3(1),      dim3(256),  0, stream>>>(h1, meta);
  k_hist2  <<<dim3(257),    dim3(256),  0, stream>>>(diffs, meta, h2);
  k_sel_lo <<<dim3(1),      dim3(256),  0, stream>>>(h2, meta);
  k_keep   <<<dim3(1),      dim3(64),   0, stream>>>(diffs, meta, keep);
  k_segment<<<dim3(64),     dim3(1024), 0, stream>>>(keep, segid, bnd, nseg);
  k_prefix <<<dim3(1),      dim3(64),   0, stream>>>(nseg, pref);
  k_pool   <<<dim3(2048),   dim3(256),  0, stream>>>(x, bnd, nseg, pref, comp);
  k_gi     <<<dim3(513, 6), dim3(256),  0, stream>>>(comp, Wih, bih, bhh, pref, gi);
  k_gru    <<<dim3(64),     dim3(512),  0, stream>>>(gi, Whh, bhh, nseg, pref, gout);
  k_scatter<<<dim3(2048),   dim3(256),  0, stream>>>(gout, segid, pref, out);
}

// Round 13
// 1784.832 us; speedup vs baseline: 1.6893x; 1.0680x over previous
//
#include <hip/hip_runtime.h>
#include <cstdint>
#include <cstddef>
#include <cmath>

// ---------------------------------------------------------------------------
// Pipeline:
//   A0 k_warm   : pull x into L2/L3 (full-GPU streaming read, ~13us)
//   A1 k_carry  : exact sequential fl cumsum chains (8 blocks producer-
//                 consumer LDS double-buffer), 256-row checkpoints only
//   A2 k_spread : 512 blocks replay each 256-row chunk from its exact carry
//   B  k_diffs  : exact numpy-pairwise variance->diffs (float4 loads)
//   C  k_hist1/k_sel_hi/k_hist2/k_sel_lo : exact top-32768 radix select
//   D  k_keep   : keep flags, stable tie ranks
//   E  k_segment: per-batch boundary lists + frame->segment map
//   F  k_prefix : ragged row offsets
//   G  k_pool   : segment means -> comp in f16 (feeds MFMA)
//   H  k_cvtw   : Wih f32 -> f16 (into dead h1/h2 region)
//      k_gim    : gi = comp @ Wih^T + biases via mfma_f32_16x16x32_f16
//                 (A/B loaded with the SAME k-chunk map -> any HW k-perm
//                 cancels; C/D map col=lane&15,row=(lane>>4)*4+j verified)
//   I  k_gru    : sequential GRU, 512 thr (at its measured per-CU L2-BW
//                 wall: spill traffic 198KB/block/step @144GB/s/CU = 687us;
//                 6 allocator configs all cap at 128 VGPR)
//   J  k_scatter: out[b,t,:] = gru_out[b, seg(t), :]
// ---------------------------------------------------------------------------

#define NPOS 65537
#define KSEL 32768u

typedef _Float16 f16x2 __attribute__((ext_vector_type(2)));
typedef _Float16 f16x8 __attribute__((ext_vector_type(8)));
typedef _Float16 frag8 __attribute__((ext_vector_type(8)));
typedef float f32x4 __attribute__((ext_vector_type(4)));

#if defined(__has_builtin)
#if __has_builtin(__builtin_amdgcn_fdot2)
#define HAVE_FDOT2 1
#endif
#endif

__device__ __forceinline__ float fdot2f(f16x2 a, f16x2 b, float c) {
#ifdef HAVE_FDOT2
  return __builtin_amdgcn_fdot2(a, b, c, false);
#else
  c += (float)a.x * (float)b.x;
  c += (float)a.y * (float)b.y;
  return c;
#endif
}

// --------------------------- A0: warm x into cache -------------------------
__global__ __launch_bounds__(256) void k_warm(const float4* __restrict__ x4,
                                              float* __restrict__ sink) {
  size_t i = (size_t)blockIdx.x * 256 + threadIdx.x;
  float4 v = x4[i];
  float s = (v.x + v.y) + (v.z + v.w);
  if (s == 1.23456789e-33f) sink[0] = s;  // deterministically false; keeps loads
}

// --------------------------- A1: carry chains ------------------------------
__global__ __launch_bounds__(256) void k_carry(const float* __restrict__ x,
                                               float* __restrict__ carr) {
  __shared__ __align__(16) float lds[2 * 256 * 64];   // 128 KiB
  const int b = blockIdx.x;
  const int sq = b >> 2;
  const int j0 = (b & 3) * 64;
  const int wid = threadIdx.x >> 6;
  const int l = threadIdx.x & 63;

  if (wid != 0) {
    // ----- stagers -----
    const int wsel = wid - 1;   // 0..2; handles 4-row groups g with g%3==wsel
    const size_t lane_off = (size_t)(l >> 4) * 256 + (size_t)(l & 15) * 4;
    for (int c = 0; c <= 256; ++c) {
      if (c < 256) {
        const float* src = x + (size_t)c * 256 * 256 + j0 + lane_off;
        float* dbase = lds + (c & 1) * 16384;
        for (int g = wsel; g < 64; g += 3) {
          __builtin_amdgcn_global_load_lds(
              (const __attribute__((address_space(1))) void*)(src + (size_t)g * 1024),
              (__attribute__((address_space(3))) void*)(dbase + g * 256),
              16, 0, 0);
        }
      }
      asm volatile("s_waitcnt vmcnt(0)" ::: "memory");
      __builtin_amdgcn_sched_barrier(0);
      __builtin_amdgcn_s_barrier();
      __builtin_amdgcn_sched_barrier(0);
    }
  } else {
    // ----- chain wave -----
#pragma clang fp contract(off)
    __builtin_amdgcn_s_barrier();        // chunk 0 staged
    __builtin_amdgcn_sched_barrier(0);
    float acc = 0.f;
    float* cw = carr + ((size_t)sq * 256) * 256 + j0 + l;
    if (sq) {
      for (int c = 0; c < 256; ++c) {
        cw[(size_t)c * 256] = acc;       // carry BEFORE chunk c's rows
        const float* lp = lds + (c & 1) * 16384 + l;
#pragma unroll 16
        for (int r = 0; r < 256; ++r) {
          float v = lp[r * 64];
          v = v * v;                     // rounded square, then add (no FMA)
          acc = acc + v;
        }
        asm volatile("s_waitcnt lgkmcnt(0)" ::: "memory");
        __builtin_amdgcn_sched_barrier(0);
        __builtin_amdgcn_s_barrier();
        __builtin_amdgcn_sched_barrier(0);
      }
    } else {
      for (int c = 0; c < 256; ++c) {
        cw[(size_t)c * 256] = acc;
        const float* lp = lds + (c & 1) * 16384 + l;
#pragma unroll 16
        for (int r = 0; r < 256; ++r) {
          float v = lp[r * 64];
          acc = acc + v;
        }
        asm volatile("s_waitcnt lgkmcnt(0)" ::: "memory");
        __builtin_amdgcn_sched_barrier(0);
        __builtin_amdgcn_s_barrier();
        __builtin_amdgcn_sched_barrier(0);
      }
    }
  }
}

// --------------------------- A2: spread chunks -----------------------------
__global__ __launch_bounds__(256) void k_spread(const float* __restrict__ x,
                                                const float* __restrict__ carr,
                                                float* __restrict__ cs1,
                                                float* __restrict__ cs2) {
#pragma clang fp contract(off)
  const int blk = blockIdx.x;
  const int sq = blk >> 8;
  const int ch = blk & 255;
  const int col = threadIdx.x;
  float* dst = sq ? cs2 : cs1;
  float c = carr[((size_t)sq * 256 + ch) * 256 + col];
  const float* gp = x + (size_t)ch * 256 * 256 + col;
  float* sp = dst + ((size_t)ch * 256 + 1) * 256 + col;
  if (ch == 0) dst[col] = 0.f;        // p=0 row (enc zero prepend)
  float buf[4][8];
#pragma unroll
  for (int d = 0; d < 3; ++d)
#pragma unroll
    for (int u = 0; u < 8; ++u)
      buf[d][u] = gp[(size_t)(d * 8 + u) * 256];
  for (int g = 0; g < 8; ++g) {
#pragma unroll
    for (int d = 0; d < 4; ++d) {
      const int s = g * 4 + d;        // 8-row group (0..31)
      if (s + 3 < 32) {
        const float* ld = gp + (size_t)(s + 3) * 8 * 256;
#pragma unroll
        for (int u = 0; u < 8; ++u)
          buf[(d + 3) & 3][u] = ld[(size_t)u * 256];
      }
#pragma unroll
      for (int u = 0; u < 8; ++u) {
        float v = buf[d][u];
        if (sq) v = v * v;
        c = c + v;
        sp[(size_t)(s * 8 + u) * 256] = c;
      }
    }
  }
}

// --------------------------- B: exact diffs --------------------------------
__device__ __forceinline__ float dterm(float ap, float am, float bp, float bm) {
#pragma clang fp contract(off)
  float s1 = ap - am;
  float s2 = bp - bm;
  float t1 = s1 * 0.5f;
  float u = s2 * 0.5f;
  return u - t1 * t1;
}

__global__ __launch_bounds__(64) void k_diffs(const float* __restrict__ cs1,
                                              const float* __restrict__ cs2,
                                              float* __restrict__ diffs) {
#pragma clang fp contract(off)
  int p = blockIdx.x * 64 + threadIdx.x;
  if (p >= NPOS) return;
  if (p == 0 || p == NPOS - 1) { diffs[p] = 1e10f; return; }
  const float4* am4 = (const float4*)(cs1 + (size_t)(p - 1) * 256);
  const float4* ap4 = (const float4*)(cs1 + (size_t)(p + 1) * 256);
  const float4* bm4 = (const float4*)(cs2 + (size_t)(p - 1) * 256);
  const float4* bp4 = (const float4*)(cs2 + (size_t)(p + 1) * 256);
  float blk[2];
  for (int half = 0; half < 2; ++half) {
    float r[8];
    for (int i = 0; i < 16; ++i) {
      int q = half * 32 + i * 2;
      float4 a0 = ap4[q], m0 = am4[q], b0 = bp4[q], n0 = bm4[q];
      float4 a1 = ap4[q + 1], m1 = am4[q + 1], b1 = bp4[q + 1], n1 = bm4[q + 1];
      float e0 = dterm(a0.x, m0.x, b0.x, n0.x);
      float e1 = dterm(a0.y, m0.y, b0.y, n0.y);
      float e2 = dterm(a0.z, m0.z, b0.z, n0.z);
      float e3 = dterm(a0.w, m0.w, b0.w, n0.w);
      float e4 = dterm(a1.x, m1.x, b1.x, n1.x);
      float e5 = dterm(a1.y, m1.y, b1.y, n1.y);
      float e6 = dterm(a1.z, m1.z, b1.z, n1.z);
      float e7 = dterm(a1.w, m1.w, b1.w, n1.w);
      if (i == 0) {
        r[0] = e0; r[1] = e1; r[2] = e2; r[3] = e3;
        r[4] = e4; r[5] = e5; r[6] = e6; r[7] = e7;
      } else {
        r[0] += e0; r[1] += e1; r[2] += e2; r[3] += e3;
        r[4] += e4; r[5] += e5; r[6] += e6; r[7] += e7;
      }
    }
    blk[half] = ((r[0] + r[1]) + (r[2] + r[3])) + ((r[4] + r[5]) + (r[6] + r[7]));
  }
  float mean = (blk[0] + blk[1]) / 256.0f;
  float mx = mean > 0.0f ? mean : 0.0f;
  diffs[p] = (float)::sqrt((double)mx);
}

// --------------------------- C: radix select -------------------------------
__global__ void k_hist1(const float* __restrict__ diffs, unsigned* __restrict__ h1) {
  int p = blockIdx.x * 256 + threadIdx.x;
  if (p >= NPOS) return;
  unsigned key = __float_as_uint(diffs[p]);
  atomicAdd(&h1[key >> 16], 1u);
}

__global__ void k_sel_hi(const unsigned* __restrict__ h1, unsigned* __restrict__ meta) {
  __shared__ unsigned loc[256];
  int t = threadIdx.x;
  unsigned s = 0;
  for (int i = 0; i < 256; ++i) s += h1[t * 256 + i];
  loc[t] = s;
  __syncthreads();
  if (t == 0) {
    unsigned run = 0; int tt = 255;
    for (; tt > 0; --tt) { if (run + loc[tt] >= KSEL) break; run += loc[tt]; }
    unsigned r2 = run;
    for (int i = 255; i >= 0; --i) {
      unsigned c = h1[tt * 256 + i];
      if (r2 + c >= KSEL) { meta[0] = (unsigned)(tt * 256 + i); meta[1] = r2; break; }
      r2 += c;
    }
  }
}

__global__ void k_hist2(const float* __restrict__ diffs, const unsigned* __restrict__ meta,
                        unsigned* __restrict__ h2) {
  int p = blockIdx.x * 256 + threadIdx.x;
  if (p >= NPOS) return;
  unsigned key = __float_as_uint(diffs[p]);
  if ((key >> 16) == meta[0]) atomicAdd(&h2[key & 0xffffu], 1u);
}

__global__ void k_sel_lo(const unsigned* __restrict__ h2, unsigned* __restrict__ meta) {
  __shared__ unsigned loc[256];
  int t = threadIdx.x;
  unsigned s = 0;
  for (int i = 0; i < 256; ++i) s += h2[t * 256 + i];
  loc[t] = s;
  __syncthreads();
  if (t == 0) {
    unsigned remaining = KSEL - meta[1];
    unsigned run = 0; int tt = 255;
    for (; tt > 0; --tt) { if (run + loc[tt] >= remaining) break; run += loc[tt]; }
    unsigned r2 = run;
    for (int i = 255; i >= 0; --i) {
      unsigned c = h2[tt * 256 + i];
      if (r2 + c >= remaining) {
        meta[2] = (meta[0] << 16) | (unsigned)(tt * 256 + i);
        meta[3] = remaining - r2;
        break;
      }
      r2 += c;
    }
  }
}

// --------------------------- D: keep flags ---------------------------------
__global__ __launch_bounds__(64) void k_keep(const float* __restrict__ diffs,
                                             const unsigned* __restrict__ meta,
                                             unsigned char* __restrict__ keep) {
  int lane = threadIdx.x;
  unsigned Kstar = meta[2], need = meta[3];
  unsigned base = 0;
  float v[4], nv[4];
#pragma unroll
  for (int q = 0; q < 4; ++q) nv[q] = diffs[q * 64 + lane];
  for (int it = 0; it < 257; ++it) {
#pragma unroll
    for (int q = 0; q < 4; ++q) v[q] = nv[q];
    if (it < 256) {
      int nb = (it + 1) * 256;
#pragma unroll
      for (int q = 0; q < 4; ++q) {
        int idx = nb + q * 64 + lane;
        nv[q] = (idx < NPOS) ? diffs[idx] : 0.f;
      }
    }
#pragma unroll
    for (int q = 0; q < 4; ++q) {
      int p = it * 256 + q * 64 + lane;
      bool valid = p < NPOS;
      unsigned key = valid ? __float_as_uint(v[q]) : 0u;
      bool eq = valid && (key == Kstar);
      unsigned long long m = __ballot(eq);
      unsigned rank = base + (unsigned)__popcll(m & ((1ull << lane) - 1ull));
      bool k = valid && ((key > Kstar) || (eq && rank < need) || ((p & 1023) == 0));
      if (valid) keep[p] = (unsigned char)k;
      base += (unsigned)__popcll(m);
    }
  }
}

// --------------------------- E: per-batch segments -------------------------
__global__ __launch_bounds__(1024) void k_segment(const unsigned char* __restrict__ keep,
                                                  int* __restrict__ segid,
                                                  int* __restrict__ bnd,
                                                  int* __restrict__ nseg) {
  __shared__ int s[1024];
  int b = blockIdx.x, t = threadIdx.x;
  int f = (t >= 1) ? (int)keep[b * 1024 + t] : 0;
  s[t] = f;
  __syncthreads();
  for (int off = 1; off < 1024; off <<= 1) {
    int v = s[t];
    int add = (t >= off) ? s[t - off] : 0;
    __syncthreads();
    s[t] = v + add;
    __syncthreads();
  }
  int sc = s[t];
  segid[b * 1024 + t] = sc;
  if (f) bnd[b * 1026 + sc] = t;
  if (t == 0) bnd[b * 1026] = 0;
  if (t == 1023) {
    int m = sc + 1;
    nseg[b] = m;
    bnd[b * 1026 + m] = 1024;
  }
}

__global__ __launch_bounds__(64) void k_prefix(const int* __restrict__ nseg,
                                               int* __restrict__ pref) {
  int lane = threadIdx.x;
  int s = nseg[lane];
  for (int off = 1; off < 64; off <<= 1) {
    int u = __shfl_up(s, off);
    if (lane >= off) s += u;
  }
  pref[lane + 1] = s;
  if (lane == 0) pref[0] = 0;
}

// --------------------------- G: segment means (f16 out) --------------------
__global__ __launch_bounds__(256) void k_pool(const float* __restrict__ x,
                                              const int* __restrict__ bnd,
                                              const int* __restrict__ nseg,
                                              const int* __restrict__ pref,
                                              _Float16* __restrict__ compH) {
  int d = threadIdx.x;
  for (int s = 0; s < 32; ++s) {
    int sid = blockIdx.x * 32 + s;
    int b = sid >> 10, li = sid & 1023;
    if (li >= nseg[b]) continue;
    int s0 = bnd[b * 1026 + li], e0 = bnd[b * 1026 + li + 1];
    float acc = 0.f;
    for (int t = s0; t < e0; ++t) acc += x[((size_t)b * 1024 + t) * 256 + d];
    compH[((size_t)pref[b] + li) * 256 + d] = (_Float16)(acc / (float)(e0 - s0));
  }
}

// --------------------------- H: Wih f32->f16 -------------------------------
__global__ __launch_bounds__(256) void k_cvtw(const float* __restrict__ Wih,
                                              _Float16* __restrict__ WihH) {
  size_t i = (size_t)blockIdx.x * 256 + threadIdx.x;   // 768*256 total
  WihH[i] = (_Float16)Wih[i];
}

// --------------------------- H: gi GEMM via MFMA f16 -----------------------
// gi[r,c] = sum_k comp[r,k]*Wih[c,k] + bih[c] + (c<512 ? bhh[c] : 0)
// 64x64 tile/block, 4 waves in 2x2, each wave 32x32 = 2x2 mfma 16x16x32.
// A and B frags both loaded as "row l&15, 8 contiguous f16 at k-chunk
// (l>>4)*8" -- identical k maps on A and B make any HW k-permutation cancel.
// C/D: col = lane&15, row = (lane>>4)*4 + j  [m89-verified].
// Rows >= total produce garbage in unread gi rows (buffer sized 32832).
__global__ __launch_bounds__(256) void k_gim(const _Float16* __restrict__ compH,
                                             const _Float16* __restrict__ WihH,
                                             const float* __restrict__ bih,
                                             const float* __restrict__ bhh,
                                             const int* __restrict__ pref,
                                             float* __restrict__ gi) {
  int total = pref[64];
  int r0 = blockIdx.x * 64;
  if (r0 >= total) return;
  int c0 = blockIdx.y * 64;
  int wid = threadIdx.x >> 6;
  int wr = wid >> 1, wc = wid & 1;
  int l = threadIdx.x & 63;
  int lrow = l & 15;
  int koff = (l >> 4) * 8;

  f32x4 acc00, acc01, acc10, acc11;
#pragma unroll
  for (int j = 0; j < 4; ++j) { acc00[j] = 0.f; acc01[j] = 0.f; acc10[j] = 0.f; acc11[j] = 0.f; }

  const _Float16* aBase0 = compH + (size_t)(r0 + wr * 32 + lrow) * 256 + koff;
  const _Float16* aBase1 = aBase0 + (size_t)16 * 256;
  const _Float16* bBase0 = WihH + (size_t)(c0 + wc * 32 + lrow) * 256 + koff;
  const _Float16* bBase1 = bBase0 + (size_t)16 * 256;

#pragma unroll
  for (int k0 = 0; k0 < 256; k0 += 32) {
    frag8 a0 = *(const frag8*)(aBase0 + k0);
    frag8 a1 = *(const frag8*)(aBase1 + k0);
    frag8 b0 = *(const frag8*)(bBase0 + k0);
    frag8 b1 = *(const frag8*)(bBase1 + k0);
    acc00 = __builtin_amdgcn_mfma_f32_16x16x32_f16(a0, b0, acc00, 0, 0, 0);
    acc01 = __builtin_amdgcn_mfma_f32_16x16x32_f16(a0, b1, acc01, 0, 0, 0);
    acc10 = __builtin_amdgcn_mfma_f32_16x16x32_f16(a1, b0, acc10, 0, 0, 0);
    acc11 = __builtin_amdgcn_mfma_f32_16x16x32_f16(a1, b1, acc11, 0, 0, 0);
  }

  int ccol0 = c0 + wc * 32 + (l & 15);
  int crow0 = r0 + wr * 32 + (l >> 4) * 4;
  float bias0 = bih[ccol0] + (ccol0 < 512 ? bhh[ccol0] : 0.f);
  int ccol1 = ccol0 + 16;
  float bias1 = bih[ccol1] + (ccol1 < 512 ? bhh[ccol1] : 0.f);
#pragma unroll
  for (int j = 0; j < 4; ++j) {
    gi[(size_t)(crow0 + j) * 768 + ccol0] = acc00[j] + bias0;
    gi[(size_t)(crow0 + j) * 768 + ccol1] = acc01[j] + bias1;
    gi[(size_t)(crow0 + 16 + j) * 768 + ccol0] = acc10[j] + bias0;
    gi[(size_t)(crow0 + 16 + j) * 768 + ccol1] = acc11[j] + bias1;
  }
}

// --------------------------- I: GRU ----------------------------------------
// 64 blocks x 512 threads (8 waves, 2/SIMD). At its measured per-CU L2 BW
// wall: the 128-VGPR cap (6 allocator configs) forces ~198KB/block/step of
// weight traffic at 144 GB/s/CU -> 1.34us/step. Left as-is.
__global__ __attribute__((amdgpu_waves_per_eu(2, 2)))
__launch_bounds__(512) void k_gru(const float* __restrict__ gi,
                                  const float* __restrict__ Whh,
                                  const float* __restrict__ bhh,
                                  const int* __restrict__ nseg,
                                  const int* __restrict__ pref,
                                  float* __restrict__ gout) {
  const int b = blockIdx.x;
  const int t = threadIdx.x;
  const int m = nseg[b];
  const size_t base = (size_t)pref[b];
  const int half = t >> 8;                 // wave-uniform (waves 0-3 / 4-7)
  const int pr = t & 255;
  const int k0 = half * 128;

  f16x2 wr[64], wz[64], wn[64];            // 192 f16x2 of weights
#pragma unroll
  for (int i = 0; i < 32; ++i) {
    float4 v = *(const float4*)(Whh + (size_t)pr * 256 + k0 + i * 4);
    f16x2 ra; ra.x = (_Float16)v.x; ra.y = (_Float16)v.y; wr[2 * i] = ra;
    f16x2 rb; rb.x = (_Float16)v.z; rb.y = (_Float16)v.w; wr[2 * i + 1] = rb;
    float4 u = *(const float4*)(Whh + (size_t)(256 + pr) * 256 + k0 + i * 4);
    f16x2 za; za.x = (_Float16)u.x; za.y = (_Float16)u.y; wz[2 * i] = za;
    f16x2 zb; zb.x = (_Float16)u.z; zb.y = (_Float16)u.w; wz[2 * i + 1] = zb;
    float4 q = *(const float4*)(Whh + (size_t)(512 + pr) * 256 + k0 + i * 4);
    f16x2 na; na.x = (_Float16)q.x; na.y = (_Float16)q.y; wn[2 * i] = na;
    f16x2 nb; nb.x = (_Float16)q.z; nb.y = (_Float16)q.w; wn[2 * i + 1] = nb;
  }

  __shared__ f16x8 hbuf8[32];     // h as f16 (256 vals); [half*16+i] uniform
  __shared__ float2 pp2[768];     // per-row {half0, half1} partials

  float bn = (t < 256) ? bhh[512 + t] : 0.f;
  float hreg = 0.f;               // finish thread t<256 owns h[t] in f32
  if (t < 32) {
    f16x8 z = (f16x8)(_Float16)0.f;
    hbuf8[t] = z;
  }
  __syncthreads();

  float cr = 0.f, cz = 0.f, cn = 0.f;
  if (t < 256) {
    const float* g0 = gi + base * 768;
    cr = g0[t]; cz = g0[256 + t]; cn = g0[512 + t];
  }

  for (int l = 0; l < m; ++l) {
    float nr = 0.f, nz = 0.f, nn = 0.f;
    if (t < 256 && l + 1 < m) {            // prefetch next step's gi
      const float* g1 = gi + (base + l + 1) * 768;
      nr = g1[t]; nz = g1[256 + t]; nn = g1[512 + t];
    }
    float ar0 = 0.f, ar1 = 0.f, az0 = 0.f, az1 = 0.f, an0 = 0.f, an1 = 0.f;
#pragma unroll
    for (int i = 0; i < 16; ++i) {
      f16x8 hv = hbuf8[half * 16 + i];     // uniform ds_read_b128
      f16x2 p0; p0.x = hv[0]; p0.y = hv[1];
      f16x2 p1; p1.x = hv[2]; p1.y = hv[3];
      f16x2 p2; p2.x = hv[4]; p2.y = hv[5];
      f16x2 p3; p3.x = hv[6]; p3.y = hv[7];
      ar0 = fdot2f(wr[4 * i + 0], p0, ar0);
      ar1 = fdot2f(wr[4 * i + 1], p1, ar1);
      ar0 = fdot2f(wr[4 * i + 2], p2, ar0);
      ar1 = fdot2f(wr[4 * i + 3], p3, ar1);
      az0 = fdot2f(wz[4 * i + 0], p0, az0);
      az1 = fdot2f(wz[4 * i + 1], p1, az1);
      az0 = fdot2f(wz[4 * i + 2], p2, az0);
      az1 = fdot2f(wz[4 * i + 3], p3, az1);
      an0 = fdot2f(wn[4 * i + 0], p0, an0);
      an1 = fdot2f(wn[4 * i + 1], p1, an1);
      an0 = fdot2f(wn[4 * i + 2], p2, an0);
      an1 = fdot2f(wn[4 * i + 3], p3, an1);
    }
    float* ppf = (float*)pp2;
    ppf[pr * 2 + half] = ar0 + ar1;
    ppf[(256 + pr) * 2 + half] = az0 + az1;
    ppf[(512 + pr) * 2 + half] = an0 + an1;
    asm volatile("s_waitcnt lgkmcnt(0)" ::: "memory");
    __builtin_amdgcn_sched_barrier(0);
    __builtin_amdgcn_s_barrier();
    __builtin_amdgcn_sched_barrier(0);
    if (t < 256) {
      float2 qr = pp2[t];
      float2 qz = pp2[256 + t];
      float2 qn = pp2[512 + t];
      float sr = qr.x + qr.y;
      float sz = qz.x + qz.y;
      float sn = qn.x + qn.y + bn;
      float r = 1.f / (1.f + __expf(-(cr + sr)));
      float z = 1.f / (1.f + __expf(-(cz + sz)));
      float arg = cn + r * sn;
      float n = 2.f / (1.f + __expf(-2.f * arg)) - 1.f;   // tanh
      float hnew = (1.f - z) * n + z * hreg;
      hreg = hnew;
      ((_Float16*)hbuf8)[t] = (_Float16)hnew;
      gout[(base + l) * 256 + t] = hnew;
    }
    cr = nr; cz = nz; cn = nn;
    asm volatile("s_waitcnt lgkmcnt(0)" ::: "memory");
    __builtin_amdgcn_sched_barrier(0);
    __builtin_amdgcn_s_barrier();
    __builtin_amdgcn_sched_barrier(0);
  }
}

// --------------------------- J: scatter ------------------------------------
__global__ __launch_bounds__(256) void k_scatter(const float* __restrict__ gout,
                                                 const int* __restrict__ segid,
                                                 const int* __restrict__ pref,
                                                 float* __restrict__ out) {
  int d = threadIdx.x;
  for (int rr = 0; rr < 32; ++rr) {
    int row = blockIdx.x * 32 + rr;
    int b = row >> 10;
    int l = segid[row];
    out[(size_t)row * 256 + d] = gout[((size_t)pref[b] + l) * 256 + d];
  }
}

// ---------------------------------------------------------------------------
extern "C" void kernel_launch(void* const* d_in, const int* in_sizes, int n_in,
                              void* d_out, int out_size, void* d_ws, size_t ws_size,
                              hipStream_t stream) {
  const float* x   = (const float*)d_in[0];
  const float* Wih = (const float*)d_in[1];
  const float* Whh = (const float*)d_in[2];
  const float* bih = (const float*)d_in[3];
  const float* bhh = (const float*)d_in[4];
  float* out = (float*)d_out;
  char* w = (char*)d_ws;

  const size_t o_cs1   = 0;
  const size_t o_cs2   = 67110912;
  const size_t o_diffs = 134221824;
  const size_t o_h1    = 134484224;   // h1 (256KB) + h2 (256KB); reused as WihH after select
  const size_t o_h2    = 134746368;
  const size_t o_meta  = 135008512;
  const size_t o_keep  = 135008768;
  const size_t o_segid = 135074560;
  const size_t o_bnd   = 135336704;
  const size_t o_nseg  = 135599360;
  const size_t o_pref  = 135599616;
  const size_t o_gi    = 135600128;
  const size_t NEED    = 236460032;
  if (ws_size < NEED) return;

  float* cs1 = (float*)(w + o_cs1);
  float* cs2 = (float*)(w + o_cs2);
  float* diffs = (float*)(w + o_diffs);
  unsigned* h1 = (unsigned*)(w + o_h1);
  unsigned* h2 = (unsigned*)(w + o_h2);
  unsigned* meta = (unsigned*)(w + o_meta);
  unsigned char* keep = (unsigned char*)(w + o_keep);
  int* segid = (int*)(w + o_segid);
  int* bnd = (int*)(w + o_bnd);
  int* nseg = (int*)(w + o_nseg);
  int* pref = (int*)(w + o_pref);
  float* gi = (float*)(w + o_gi);
  float* carr = (float*)(w + o_gi);        // 512KB; dead before gi written
  _Float16* compH = (_Float16*)(w + o_cs1);  // 16.8MB; cs1 dead after k_diffs
  _Float16* WihH  = (_Float16*)(w + o_h1);   // 384KB; h1/h2 dead after select
  float* gout = cs2;                        // reuse
  float* sink = (float*)(w + o_meta + 192);

  hipMemsetAsync(h1, 0, 262144, stream);
  hipMemsetAsync(h2, 0, 262144, stream);

  k_warm   <<<dim3(16384),   dim3(256),  0, stream>>>((const float4*)x, sink);
  k_carry  <<<dim3(8),       dim3(256),  0, stream>>>(x, carr);
  k_spread <<<dim3(512),     dim3(256),  0, stream>>>(x, carr, cs1, cs2);
  k_diffs  <<<dim3(1025),    dim3(64),   0, stream>>>(cs1, cs2, diffs);
  k_hist1  <<<dim3(257),     dim3(256),  0, stream>>>(diffs, h1);
  k_sel_hi <<<dim3(1),       dim3(256),  0, stream>>>(h1, meta);
  k_hist2  <<<dim3(257),     dim3(256),  0, stream>>>(diffs, meta, h2);
  k_sel_lo <<<dim3(1),       dim3(256),  0, stream>>>(h2, meta);
  k_keep   <<<dim3(1),       dim3(64),   0, stream>>>(diffs, meta, keep);
  k_segment<<<dim3(64),      dim3(1024), 0, stream>>>(keep, segid, bnd, nseg);
  k_prefix <<<dim3(1),       dim3(64),   0, stream>>>(nseg, pref);
  k_cvtw   <<<dim3(768),     dim3(256),  0, stream>>>(Wih, WihH);
  k_pool   <<<dim3(2048),    dim3(256),  0, stream>>>(x, bnd, nseg, pref, compH);
  k_gim    <<<dim3(513, 12), dim3(256),  0, stream>>>(compH, WihH, bih, bhh, pref, gi);
  k_gru    <<<dim3(64),      dim3(512),  0, stream>>>(gi, Whh, bhh, nseg, pref, gout);
  k_scatter<<<dim3(2048),    dim3(256),  0, stream>>>(gout, segid, pref, out);
}